// Round 10
// baseline (418.244 us; speedup 1.0000x reference)
//
#include <hip/hip_runtime.h>

// GraphSAGE, linearity-restructured + bf16 MFMA:
//   out_r = nf_r@W1 + b1 + c_r*( SumNF_r@W2 + SumEF_r@We + deg_r*(b2+be) )
// c_r = max(deg_r,1). Aggregate writes RAW sums (bf16); GEMM applies c_r +
// degree-bias exactly in f32 epilogue. Weights pre-transposed bf16 Wt[col][k].

constexpr int NN = 50000;   // nodes
constexpr int NE = 800000;  // edges
constexpr int DF = 128;     // node feat
constexpr int DE = 64;      // edge feat
constexpr int EM = 128;     // embed
constexpr int KT = 320;     // total K = 128+128+64

typedef __attribute__((ext_vector_type(8))) short bf16x8;
typedef __attribute__((ext_vector_type(4))) float f32x4;

__device__ inline unsigned f2bf(float f) {            // RNE f32->bf16
    unsigned u = __float_as_uint(f);
    return (u + 0x7FFFu + ((u >> 16) & 1u)) >> 16;
}
__device__ inline float bflo(unsigned u) { return __uint_as_float(u << 16); }
__device__ inline float bfhi(unsigned u) { return __uint_as_float(u & 0xFFFF0000u); }

// ---------------- fused setup: degree+rank | nf->bf16 | Wt build ----------------
constexpr int NB_DEG = (NE + 255) / 256;            // 3125
constexpr int NB_NF  = (NN * DF / 4 + 255) / 256;   // 6250
constexpr int NB_WT  = (EM * KT + 255) / 256;       // 160

__global__ __launch_bounds__(256) void setup_kernel(
    const float* __restrict__ nf, const float* __restrict__ W,
    const float* __restrict__ We, const int* __restrict__ recv,
    int* __restrict__ deg, int* __restrict__ rank,
    unsigned short* __restrict__ nf16, unsigned short* __restrict__ Wt)
{
    const int b = blockIdx.x;
    if (b < NB_DEG) {
        const int i = b * 256 + threadIdx.x;
        if (i < NE) rank[i] = atomicAdd(&deg[recv[i]], 1);
    } else if (b < NB_DEG + NB_NF) {
        const int i = (b - NB_DEG) * 256 + threadIdx.x;   // 4 floats per thread
        const float4 v = ((const float4*)nf)[i];
        unsigned lo = f2bf(v.x) | (f2bf(v.y) << 16);
        unsigned hi = f2bf(v.z) | (f2bf(v.w) << 16);
        ((uint2*)nf16)[i] = make_uint2(lo, hi);
    } else {
        const int i = (b - NB_DEG - NB_NF) * 256 + threadIdx.x;
        if (i < EM * KT) {
            const int col = i / KT, k = i - col * KT;
            float v;
            if (k < 128)      v = W[k * 256 + col];                 // W1
            else if (k < 256) v = W[(k - 128) * 256 + 128 + col];   // W2
            else              v = We[(k - 256) * 128 + col];        // We
            Wt[i] = (unsigned short)f2bf(v);
        }
    }
}

// ---------------- 3-stage exclusive scan ----------------
__global__ __launch_bounds__(256) void scan1_kernel(const int* __restrict__ deg,
                                                    int* __restrict__ bsum)
{
    __shared__ int sh[256];
    const int t = threadIdx.x;
    const int i = blockIdx.x * 256 + t;
    sh[t] = (i < NN) ? deg[i] : 0;
    __syncthreads();
    for (int off = 128; off > 0; off >>= 1) {
        if (t < off) sh[t] += sh[t + off];
        __syncthreads();
    }
    if (t == 0) bsum[blockIdx.x] = sh[0];
}

__global__ __launch_bounds__(256) void scan2_kernel(const int* __restrict__ bsum,
                                                    int* __restrict__ boffs, int nb)
{
    __shared__ int sh[256];
    const int t = threadIdx.x;
    int v = (t < nb) ? bsum[t] : 0;
    int x = v;
    sh[t] = x; __syncthreads();
    for (int off = 1; off < 256; off <<= 1) {
        int y = (t >= off) ? sh[t - off] : 0;
        __syncthreads();
        x += y;
        sh[t] = x;
        __syncthreads();
    }
    if (t < nb) boffs[t] = x - v;
}

__global__ __launch_bounds__(256) void scan3_kernel(const int* __restrict__ deg,
                                                    const int* __restrict__ boffs,
                                                    int* __restrict__ start)
{
    __shared__ int sh[256];
    const int t = threadIdx.x;
    const int i = blockIdx.x * 256 + t;
    const int v = (i < NN) ? deg[i] : 0;
    int x = v;
    sh[t] = x; __syncthreads();
    for (int off = 1; off < 256; off <<= 1) {
        int y = (t >= off) ? sh[t - off] : 0;
        __syncthreads();
        x += y;
        sh[t] = x;
        __syncthreads();
    }
    const int base = boffs[blockIdx.x];
    if (i < NN) start[i] = base + x - v;
    if (i == NN - 1) start[NN] = base + x;
}

// ---------------- scatter (atomic-free): csr[slot] = {edge, sender} ----------------
__global__ void scatter_kernel(const int* __restrict__ recv, const int* __restrict__ rank,
                               const int* __restrict__ senders, const int* __restrict__ start,
                               int2* __restrict__ csr)
{
    int i = blockIdx.x * blockDim.x + threadIdx.x;
    if (i < NE) {
        int slot = start[recv[i]] + rank[i];
        csr[slot] = make_int2(i, senders[i]);
    }
}

// ---------------- wave-per-node RAW segment sums, predicated unroll-8 ----------------
__global__ __launch_bounds__(256) void aggregate_kernel(
    const int* __restrict__ start, const int2* __restrict__ csr,
    const unsigned short* __restrict__ nf16, const float* __restrict__ ef,
    unsigned short* __restrict__ snf16, unsigned short* __restrict__ sef16)
{
    const int wave = threadIdx.x >> 6;
    const int lane = threadIdx.x & 63;
    const int n = blockIdx.x * 4 + wave;
    if (n >= NN) return;
    const int lo = start[n], hi = start[n + 1];
    if (lo == hi) {
        *(unsigned*)&snf16[(size_t)n * DF + lane * 2] = 0;
        sef16[(size_t)n * DE + lane] = 0;
        return;
    }
    float aN0 = 0.f, aN1 = 0.f, aE = 0.f;
    for (int i = lo; i < hi; i += 8) {
        int2 c[8];
        #pragma unroll
        for (int j = 0; j < 8; ++j) c[j] = csr[min(i + j, hi - 1)];
        unsigned u[8]; float e[8];
        #pragma unroll
        for (int j = 0; j < 8; ++j) {
            u[j] = *(const unsigned*)&nf16[(size_t)c[j].y * DF + lane * 2];
            e[j] = ef[(size_t)c[j].x * DE + lane];
        }
        #pragma unroll
        for (int j = 0; j < 8; ++j) {
            const float m = (i + j < hi) ? 1.f : 0.f;
            aN0 += m * bflo(u[j]);
            aN1 += m * bfhi(u[j]);
            aE  += m * e[j];
        }
    }
    *(unsigned*)&snf16[(size_t)n * DF + lane * 2] = f2bf(aN0) | (f2bf(aN1) << 16);
    sef16[(size_t)n * DE + lane] = (unsigned short)f2bf(aE);
}

// ---------------- final GEMM (bf16 MFMA 16x16x32) ----------------
// A = [nf16 | snf16 | sef16] (M=50000, K=320), B = Wt^T. Tile 64 rows x 128 cols,
// 4 waves: wave w -> rows (w>>1)*32, cols (w&1)*64. Two acc sets: self / neighbor.
__device__ inline int swz(int row, int k) {           // byte offset, 16B-lane swizzle
    return (row * 128 + k * 2) ^ ((row & 7) << 4);
}

__global__ __launch_bounds__(256) void final_gemm(
    const unsigned short* __restrict__ nf16, const unsigned short* __restrict__ snf16,
    const unsigned short* __restrict__ sef16, const unsigned short* __restrict__ Wt,
    const float* __restrict__ Wb, const float* __restrict__ Web,
    const int* __restrict__ deg, float* __restrict__ out)
{
    __shared__ char smem[8192 + 16384];
    char* As = smem;            // 64 rows x 64 k
    char* Bt = smem + 8192;     // 128 cols x 64 k
    const int t = threadIdx.x;
    const int l = t & 63;
    const int w = t >> 6;
    const int wr = (w >> 1) * 32;
    const int wc = (w & 1) * 64;
    const int row0 = blockIdx.x * 64;

    f32x4 accS[2][4] = {};
    f32x4 accN[2][4] = {};

    for (int c = 0; c < 5; ++c) {
        if (c) __syncthreads();
        const unsigned short* srcA = (c < 2) ? nf16 + c * 64
                                   : (c < 4) ? snf16 + (c - 2) * 64
                                             : sef16;
        const int strideA = (c < 4) ? DF : DE;
        #pragma unroll
        for (int p = 0; p < 2; ++p) {
            const int row = (t >> 3) + p * 32;
            const int kb = (t & 7) * 8;
            const int node = row0 + row;
            uint4 v = make_uint4(0, 0, 0, 0);
            if (node < NN) v = *(const uint4*)&srcA[(size_t)node * strideA + kb];
            *(uint4*)(As + swz(row, kb)) = v;
        }
        #pragma unroll
        for (int p = 0; p < 4; ++p) {
            const int col = (t >> 3) + p * 32;
            const int kb = (t & 7) * 8;
            *(uint4*)(Bt + swz(col, kb)) = *(const uint4*)&Wt[(size_t)col * KT + c * 64 + kb];
        }
        __syncthreads();

        #pragma unroll
        for (int ks = 0; ks < 2; ++ks) {
            bf16x8 a[2], b[4];
            const int kf = ks * 32 + (l >> 4) * 8;
            #pragma unroll
            for (int r = 0; r < 2; ++r)
                a[r] = *(const bf16x8*)(As + swz(wr + r * 16 + (l & 15), kf));
            #pragma unroll
            for (int cc = 0; cc < 4; ++cc)
                b[cc] = *(const bf16x8*)(Bt + swz(wc + cc * 16 + (l & 15), kf));
            if (c < 2) {
                #pragma unroll
                for (int r = 0; r < 2; ++r)
                    #pragma unroll
                    for (int cc = 0; cc < 4; ++cc)
                        accS[r][cc] = __builtin_amdgcn_mfma_f32_16x16x32_bf16(
                            a[r], b[cc], accS[r][cc], 0, 0, 0);
            } else {
                #pragma unroll
                for (int r = 0; r < 2; ++r)
                    #pragma unroll
                    for (int cc = 0; cc < 4; ++cc)
                        accN[r][cc] = __builtin_amdgcn_mfma_f32_16x16x32_bf16(
                            a[r], b[cc], accN[r][cc], 0, 0, 0);
            }
        }
    }

    // epilogue: out = accS + b1 + cmax*(accN + dg*bc),  bc = b2 + be
    #pragma unroll
    for (int r = 0; r < 2; ++r) {
        #pragma unroll
        for (int j = 0; j < 4; ++j) {
            const int node = row0 + wr + r * 16 + (l >> 4) * 4 + j;
            if (node >= NN) continue;
            const float dg = (float)deg[node];
            const float cm = fmaxf(dg, 1.0f);
            #pragma unroll
            for (int cc = 0; cc < 4; ++cc) {
                const int col = wc + cc * 16 + (l & 15);
                const float b1 = Wb[col];
                const float bc = Wb[EM + col] + Web[col];
                out[(size_t)node * EM + col] =
                    accS[r][cc][j] + b1 + cm * (accN[r][cc][j] + dg * bc);
            }
        }
    }
}

extern "C" void kernel_launch(void* const* d_in, const int* in_sizes, int n_in,
                              void* d_out, int out_size, void* d_ws, size_t ws_size,
                              hipStream_t stream)
{
    (void)in_sizes; (void)n_in; (void)out_size; (void)ws_size;
    const float* nf        = (const float*)d_in[0];
    const int*   senders   = (const int*)d_in[1];
    const int*   receivers = (const int*)d_in[2];
    const float* ef        = (const float*)d_in[3];
    const float* W         = (const float*)d_in[4];
    const float* Wb        = (const float*)d_in[5];
    const float* We        = (const float*)d_in[6];
    const float* Web       = (const float*)d_in[7];
    float* out = (float*)d_out;

    char* p = (char*)d_ws;
    auto alloc = [&](size_t bytes) { void* q = p; p += (bytes + 255) & ~size_t(255); return q; };
    unsigned short* nf16  = (unsigned short*)alloc((size_t)NN * DF * 2);  // 12.8 MB
    unsigned short* snf16 = (unsigned short*)alloc((size_t)NN * DF * 2);  // 12.8 MB
    unsigned short* sef16 = (unsigned short*)alloc((size_t)NN * DE * 2);  //  6.4 MB
    unsigned short* Wt    = (unsigned short*)alloc((size_t)EM * KT * 2);  //  80 KB
    int*   deg   = (int*)  alloc((size_t)NN * sizeof(int));
    int*   start = (int*)  alloc((size_t)(NN + 1) * sizeof(int));
    int*   rank  = (int*)  alloc((size_t)NE * sizeof(int));               //  3.2 MB
    int2*  csr   = (int2*) alloc((size_t)NE * sizeof(int2));              //  6.4 MB
    int*   bsum  = (int*)  alloc(256 * sizeof(int));
    int*   boffs = (int*)  alloc(256 * sizeof(int));

    const int NB = (NN + 255) / 256;    // 196

    hipMemsetAsync(deg, 0, (size_t)NN * sizeof(int), stream);

    setup_kernel  <<<NB_DEG + NB_NF + NB_WT, 256, 0, stream>>>(
                      nf, W, We, receivers, deg, rank, nf16, Wt);
    scan1_kernel  <<<NB, 256, 0, stream>>>(deg, bsum);
    scan2_kernel  <<<1, 256, 0, stream>>>(bsum, boffs, NB);
    scan3_kernel  <<<NB, 256, 0, stream>>>(deg, boffs, start);
    scatter_kernel<<<(NE + 255) / 256, 256, 0, stream>>>(receivers, rank, senders, start, csr);
    aggregate_kernel<<<(NN + 3) / 4, 256, 0, stream>>>(start, csr, nf16, ef, snf16, sef16);
    final_gemm    <<<(NN + 63) / 64, 256, 0, stream>>>(nf16, snf16, sef16, Wt, Wb, Web, deg, out);
}